// Round 1
// 956.922 us; speedup vs baseline: 1.0240x; 1.0240x over previous
//
#include <hip/hip_runtime.h>

#define NN 50000
#define NE 800000

// ---------------- LayerNorm: one wave (64 lanes) per node, 128 cols ----------
__global__ __launch_bounds__(256) void ln_kernel(
    const float* __restrict__ x, const float* __restrict__ g,
    const float* __restrict__ b, float* __restrict__ h, int n) {
  int wid  = (blockIdx.x * blockDim.x + threadIdx.x) >> 6;
  int lane = threadIdx.x & 63;
  if (wid >= n) return;
  const float2 v = *(const float2*)(x + (size_t)wid * 128 + lane * 2);
  float sum = v.x + v.y;
  float sq  = v.x * v.x + v.y * v.y;
#pragma unroll
  for (int off = 32; off > 0; off >>= 1) {
    sum += __shfl_down(sum, off);
    sq  += __shfl_down(sq, off);
  }
  sum = __shfl(sum, 0);
  sq  = __shfl(sq, 0);
  float mu  = sum * (1.f / 128.f);
  float var = sq * (1.f / 128.f) - mu * mu;
  float inv = rsqrtf(var + 1e-5f);
  float2 gg = *(const float2*)(g + lane * 2);
  float2 bb = *(const float2*)(b + lane * 2);
  float2 o;
  o.x = (v.x - mu) * inv * gg.x + bb.x;
  o.y = (v.y - mu) * inv * gg.y + bb.y;
  *(float2*)(h + (size_t)wid * 128 + lane * 2) = o;
}

// ---------------- K=128 fp32 GEMM, row-per-lane, W via wave-uniform (scalar) loads
// Out[row][n0..n0+63] = A[row][0..127] @ W[0..127][n0..n0+63] + bias (+resid)
// No LDS, no barriers. W addresses depend only on (blockIdx.y, k) -> uniform ->
// compiler scalarizes to s_load; v_fmac uses the SGPR as the scalar operand.
__global__ __launch_bounds__(256) void gemm_rw(
    const float* __restrict__ A, const float* __restrict__ W,
    const float* __restrict__ bias, const float* __restrict__ resid,
    float* __restrict__ Out, int M, int Nw) {
  int row  = blockIdx.x * 256 + threadIdx.x;
  int n0   = blockIdx.y * 64;
  bool live = row < M;
  const float* Ar = A + (size_t)(live ? row : 0) * 128;

  float acc[64];
#pragma unroll
  for (int j = 0; j < 64; ++j) acc[j] = 0.f;

  for (int k = 0; k < 128; k += 4) {
    float4 a4 = *(const float4*)(Ar + k);
#pragma unroll
    for (int t = 0; t < 4; ++t) {
      float ak = (t == 0) ? a4.x : (t == 1) ? a4.y : (t == 2) ? a4.z : a4.w;
      const float* wr = W + (size_t)(k + t) * Nw + n0;   // wave-uniform
#pragma unroll
      for (int j = 0; j < 16; ++j) {
        float4 w = *(const float4*)(wr + 4 * j);
        acc[4 * j + 0] += ak * w.x;
        acc[4 * j + 1] += ak * w.y;
        acc[4 * j + 2] += ak * w.z;
        acc[4 * j + 3] += ak * w.w;
      }
    }
  }

  if (!live) return;
  float* o = Out + (size_t)row * Nw + n0;
  if (resid) {
    const float* r = resid + (size_t)row * Nw + n0;
#pragma unroll
    for (int j = 0; j < 16; ++j) {
      float4 bb = *(const float4*)(bias + n0 + 4 * j);   // uniform
      float4 rv = *(const float4*)(r + 4 * j);
      float4 ov;
      ov.x = acc[4 * j + 0] + bb.x + rv.x;
      ov.y = acc[4 * j + 1] + bb.y + rv.y;
      ov.z = acc[4 * j + 2] + bb.z + rv.z;
      ov.w = acc[4 * j + 3] + bb.w + rv.w;
      *(float4*)(o + 4 * j) = ov;
    }
  } else {
#pragma unroll
    for (int j = 0; j < 16; ++j) {
      float4 bb = *(const float4*)(bias + n0 + 4 * j);   // uniform
      float4 ov;
      ov.x = acc[4 * j + 0] + bb.x;
      ov.y = acc[4 * j + 1] + bb.y;
      ov.z = acc[4 * j + 2] + bb.z;
      ov.w = acc[4 * j + 3] + bb.w;
      *(float4*)(o + 4 * j) = ov;
    }
  }
}

// ---------------- CSR build ----------------
__global__ __launch_bounds__(256) void count_kernel(
    const int* __restrict__ ei, int* __restrict__ cnt, int E) {
  int e = blockIdx.x * blockDim.x + threadIdx.x;
  if (e >= E) return;
  atomicAdd(&cnt[ei[E + e]], 1);  // dst row
}

// single-block exclusive scan of cnt[0..n) -> row_start[0..n]
__global__ __launch_bounds__(1024) void scan_kernel(
    const int* __restrict__ cnt, int* __restrict__ row_start, int n) {
  __shared__ int sums[1024];
  int tid = threadIdx.x;
  const int CH = (n + 1023) / 1024;
  int begin = tid * CH;
  int end   = min(begin + CH, n);
  int s = 0;
  for (int i = begin; i < end; ++i) s += cnt[i];
  sums[tid] = s;
  __syncthreads();
  for (int off = 1; off < 1024; off <<= 1) {
    int t = (tid >= off) ? sums[tid - off] : 0;
    __syncthreads();
    if (tid >= off) sums[tid] += t;
    __syncthreads();
  }
  int run = sums[tid] - s;  // exclusive prefix at chunk start
  for (int i = begin; i < end; ++i) {
    row_start[i] = run;
    run += cnt[i];
  }
  if (tid == 1023) row_start[n] = run;  // total (= E)
}

__global__ __launch_bounds__(256) void scatter_kernel(
    const int* __restrict__ ei, int* __restrict__ cursor,
    int* __restrict__ perm, int E) {
  int e = blockIdx.x * blockDim.x + threadIdx.x;
  if (e >= E) return;
  int pos = atomicAdd(&cursor[ei[E + e]], 1);
  perm[pos] = e;
}

// ---------------- Fused per-node attention (online softmax, no atomics) -----
// One wave per node. Lane l covers channels 2l, 2l+1 (head l>>3).
// 2-edge unroll: doubles memory-level parallelism, halves the serial
// online-softmax chain length (one max3 + one rescale per pair).
__global__ __launch_bounds__(256) void fused_attn(
    const float* __restrict__ qkv, const float* __restrict__ edge_attr,
    const int* __restrict__ ei, const int* __restrict__ row_start,
    const int* __restrict__ perm, float* __restrict__ agg, int N, int E) {
  int node = (blockIdx.x * blockDim.x + threadIdx.x) >> 6;
  if (node >= N) return;
  int lane = threadIdx.x & 63;
  int ch   = lane * 2;  // == (lane>>3)*16 + (lane&7)*2

  float2 q2 = *(const float2*)(qkv + (size_t)node * 384 + ch);

  float m = -INFINITY, l = 0.f;
  float2 acc = make_float2(0.f, 0.f);

  int beg  = row_start[node];
  int stop = row_start[node + 1];
  int i = beg;
  for (; i + 2 <= stop; i += 2) {
    int e0 = perm[i], e1 = perm[i + 1];
    int s0 = ei[e0], s1 = ei[e1];
    float2 k0 = *(const float2*)(qkv + (size_t)s0 * 384 + 128 + ch);
    float2 k1 = *(const float2*)(qkv + (size_t)s1 * 384 + 128 + ch);
    float2 a0 = *(const float2*)(edge_attr + (size_t)e0 * 128 + ch);
    float2 a1 = *(const float2*)(edge_attr + (size_t)e1 * 128 + ch);
    float2 v0 = *(const float2*)(qkv + (size_t)s0 * 384 + 256 + ch);
    float2 v1 = *(const float2*)(qkv + (size_t)s1 * 384 + 256 + ch);
    float p0 = q2.x * (k0.x + a0.x) + q2.y * (k0.y + a0.y);
    float p1 = q2.x * (k1.x + a1.x) + q2.y * (k1.y + a1.y);
    p0 += __shfl_xor(p0, 1);
    p1 += __shfl_xor(p1, 1);
    p0 += __shfl_xor(p0, 2);
    p1 += __shfl_xor(p1, 2);
    p0 += __shfl_xor(p0, 4);
    p1 += __shfl_xor(p1, 4);
    float sc0 = p0 * 0.25f;  // D_HEAD^-0.5
    float sc1 = p1 * 0.25f;
    float mn = fmaxf(fmaxf(m, sc0), sc1);     // -> v_max3_f32
    float scale = __expf(m - mn);             // m=-inf first pair -> 0, no NaN
    float pe0   = __expf(sc0 - mn);
    float pe1   = __expf(sc1 - mn);
    l = l * scale + pe0 + pe1;
    acc.x = acc.x * scale + pe0 * v0.x + pe1 * v1.x;
    acc.y = acc.y * scale + pe0 * v0.y + pe1 * v1.y;
    m = mn;
  }
  if (i < stop) {  // odd tail
    int e   = perm[i];
    int src = ei[e];
    float2 kv = *(const float2*)(qkv + (size_t)src * 384 + 128 + ch);
    float2 ea = *(const float2*)(edge_attr + (size_t)e * 128 + ch);
    float p = q2.x * (kv.x + ea.x) + q2.y * (kv.y + ea.y);
    p += __shfl_xor(p, 1);
    p += __shfl_xor(p, 2);
    p += __shfl_xor(p, 4);
    float s  = p * 0.25f;
    float mn = fmaxf(m, s);
    float scale = __expf(m - mn);
    float pe    = __expf(s - mn);
    l = l * scale + pe;
    float2 vv = *(const float2*)(qkv + (size_t)src * 384 + 256 + ch);
    acc.x = acc.x * scale + pe * vv.x;
    acc.y = acc.y * scale + pe * vv.y;
    m = mn;
  }
  float inv = 1.f / fmaxf(l, 1e-16f);
  float2 o = make_float2(acc.x * inv, acc.y * inv);
  *(float2*)(agg + (size_t)node * 128 + ch) = o;
}

extern "C" void kernel_launch(void* const* d_in, const int* in_sizes, int n_in,
                              void* d_out, int out_size, void* d_ws,
                              size_t ws_size, hipStream_t stream) {
  const float* x         = (const float*)d_in[0];
  const float* edge_attr = (const float*)d_in[1];
  const float* qkv_w     = (const float*)d_in[2];
  const float* qkv_b     = (const float*)d_in[3];
  const float* out_w     = (const float*)d_in[4];
  const float* out_b     = (const float*)d_in[5];
  const float* ln_g      = (const float*)d_in[6];
  const float* ln_b      = (const float*)d_in[7];
  const int*   ei        = (const int*)d_in[8];
  float* out = (float*)d_out;

  const int N = NN, E = NE;
  float* h         = (float*)d_ws;                        // N*128 f
  float* qkv       = h + (size_t)N * 128;                 // N*384 f
  int*   cnt       = (int*)(qkv + (size_t)N * 384);       // N
  int*   row_start = cnt + N;                             // N+1
  int*   cursor    = row_start + N + 1;                   // N
  int*   perm      = cursor + N;                          // E
  float* agg       = h;  // h dead after GEMM1; fused_attn writes (no memset)

  // --- CSR build (independent of LN/GEMM, same stream => ordered) ---
  hipMemsetAsync(cnt, 0, (size_t)N * 4, stream);
  count_kernel<<<(E + 255) / 256, 256, 0, stream>>>(ei, cnt, E);
  scan_kernel<<<1, 1024, 0, stream>>>(cnt, row_start, N);
  hipMemcpyAsync(cursor, row_start, (size_t)N * 4, hipMemcpyDeviceToDevice,
                 stream);
  scatter_kernel<<<(E + 255) / 256, 256, 0, stream>>>(ei, cursor, perm, E);

  // --- 1. LayerNorm ---
  ln_kernel<<<(N * 64 + 255) / 256, 256, 0, stream>>>(x, ln_g, ln_b, h, N);

  // --- 2. QKV projection: rows-per-lane, 6 column blocks of 64 ---
  dim3 g1((N + 255) / 256, 384 / 64);
  gemm_rw<<<g1, 256, 0, stream>>>(h, qkv_w, qkv_b, nullptr, qkv, N, 384);

  // --- 3. fused attention (scores + softmax + aggregate) ---
  fused_attn<<<(N * 64 + 255) / 256, 256, 0, stream>>>(
      qkv, edge_attr, ei, row_start, perm, agg, N, E);

  // --- 4. output projection + bias + residual: 2 column blocks of 64 ---
  dim3 g2((N + 255) / 256, 128 / 64);
  gemm_rw<<<g2, 256, 0, stream>>>(agg, out_w, out_b, x, out, N, 128);
}

// Round 2
// 908.179 us; speedup vs baseline: 1.0790x; 1.0537x over previous
//
#include <hip/hip_runtime.h>

#define NN 50000
#define NE 800000

// ---------------- Fused LayerNorm + QKV GEMM ------------------------------
// One output row per lane; column block of 64 per blockIdx.y.
// Pass 1 computes LN stats in-thread (row is thread-private, no shuffles);
// pass 2 re-reads the row (L2-hot), normalizes on the fly, FMAs against W
// read via wave-uniform addresses (scalarized to s_load -> SGPR broadcast).
__global__ __launch_bounds__(256) void ln_qkv(
    const float* __restrict__ x, const float* __restrict__ g,
    const float* __restrict__ b, const float* __restrict__ W,
    const float* __restrict__ bias, float* __restrict__ Out, int M) {
  const int Nw = 384;
  int row  = blockIdx.x * 256 + threadIdx.x;
  int n0   = blockIdx.y * 64;
  bool live = row < M;
  const float* xr = x + (size_t)(live ? row : 0) * 128;

  // pass 1: mean/var
  float sum = 0.f, sq = 0.f;
  for (int k = 0; k < 128; k += 4) {
    float4 a = *(const float4*)(xr + k);
    sum += a.x + a.y + a.z + a.w;
    sq  += a.x * a.x + a.y * a.y + a.z * a.z + a.w * a.w;
  }
  float mu  = sum * (1.f / 128.f);
  float var = sq * (1.f / 128.f) - mu * mu;
  float inv = rsqrtf(var + 1e-5f);

  float acc[64];
#pragma unroll
  for (int j = 0; j < 64; ++j) acc[j] = 0.f;

  // pass 2: normalize + GEMM
  for (int k = 0; k < 128; k += 4) {
    float4 a  = *(const float4*)(xr + k);
    float4 gg = *(const float4*)(g + k);   // uniform
    float4 bb = *(const float4*)(b + k);   // uniform
    float an[4];
    an[0] = (a.x - mu) * inv * gg.x + bb.x;
    an[1] = (a.y - mu) * inv * gg.y + bb.y;
    an[2] = (a.z - mu) * inv * gg.z + bb.z;
    an[3] = (a.w - mu) * inv * gg.w + bb.w;
#pragma unroll
    for (int t = 0; t < 4; ++t) {
      float ak = an[t];
      const float* wr = W + (size_t)(k + t) * Nw + n0;  // wave-uniform
#pragma unroll
      for (int j = 0; j < 16; ++j) {
        float4 w = *(const float4*)(wr + 4 * j);
        acc[4 * j + 0] += ak * w.x;
        acc[4 * j + 1] += ak * w.y;
        acc[4 * j + 2] += ak * w.z;
        acc[4 * j + 3] += ak * w.w;
      }
    }
  }

  if (!live) return;
  float* o = Out + (size_t)row * Nw + n0;
#pragma unroll
  for (int j = 0; j < 16; ++j) {
    float4 bb = *(const float4*)(bias + n0 + 4 * j);  // uniform
    float4 ov;
    ov.x = acc[4 * j + 0] + bb.x;
    ov.y = acc[4 * j + 1] + bb.y;
    ov.z = acc[4 * j + 2] + bb.z;
    ov.w = acc[4 * j + 3] + bb.w;
    *(float4*)(o + 4 * j) = ov;
  }
}

// ---------------- K=128 fp32 GEMM, row-per-lane (out-projection) -----------
__global__ __launch_bounds__(256) void gemm_rw(
    const float* __restrict__ A, const float* __restrict__ W,
    const float* __restrict__ bias, const float* __restrict__ resid,
    float* __restrict__ Out, int M, int Nw) {
  int row  = blockIdx.x * 256 + threadIdx.x;
  int n0   = blockIdx.y * 64;
  bool live = row < M;
  const float* Ar = A + (size_t)(live ? row : 0) * 128;

  float acc[64];
#pragma unroll
  for (int j = 0; j < 64; ++j) acc[j] = 0.f;

  for (int k = 0; k < 128; k += 4) {
    float4 a4 = *(const float4*)(Ar + k);
#pragma unroll
    for (int t = 0; t < 4; ++t) {
      float ak = (t == 0) ? a4.x : (t == 1) ? a4.y : (t == 2) ? a4.z : a4.w;
      const float* wr = W + (size_t)(k + t) * Nw + n0;  // wave-uniform
#pragma unroll
      for (int j = 0; j < 16; ++j) {
        float4 w = *(const float4*)(wr + 4 * j);
        acc[4 * j + 0] += ak * w.x;
        acc[4 * j + 1] += ak * w.y;
        acc[4 * j + 2] += ak * w.z;
        acc[4 * j + 3] += ak * w.w;
      }
    }
  }

  if (!live) return;
  float* o = Out + (size_t)row * Nw + n0;
  const float* r = resid + (size_t)row * Nw + n0;
#pragma unroll
  for (int j = 0; j < 16; ++j) {
    float4 bb = *(const float4*)(bias + n0 + 4 * j);  // uniform
    float4 rv = *(const float4*)(r + 4 * j);
    float4 ov;
    ov.x = acc[4 * j + 0] + bb.x + rv.x;
    ov.y = acc[4 * j + 1] + bb.y + rv.y;
    ov.z = acc[4 * j + 2] + bb.z + rv.z;
    ov.w = acc[4 * j + 3] + bb.w + rv.w;
    *(float4*)(o + 4 * j) = ov;
  }
}

// ---------------- CSR build ----------------
__global__ __launch_bounds__(256) void count_kernel(
    const int* __restrict__ ei, int* __restrict__ cnt, int E) {
  int e = blockIdx.x * blockDim.x + threadIdx.x;
  if (e >= E) return;
  atomicAdd(&cnt[ei[E + e]], 1);  // dst row
}

// coalesced per-block sums of cnt
__global__ __launch_bounds__(256) void block_sums(
    const int* __restrict__ cnt, int* __restrict__ bsum, int n) {
  int i = blockIdx.x * 256 + threadIdx.x;
  int v = (i < n) ? cnt[i] : 0;
#pragma unroll
  for (int o = 32; o > 0; o >>= 1) v += __shfl_down(v, o);
  __shared__ int ws[4];
  if ((threadIdx.x & 63) == 0) ws[threadIdx.x >> 6] = v;
  __syncthreads();
  if (threadIdx.x == 0) bsum[blockIdx.x] = ws[0] + ws[1] + ws[2] + ws[3];
}

// grid-wide scan: block offset from bsum prefix + intra-block shfl scan.
// Writes row_start AND cursor (no memcpy); row_start[n] = total (known = E).
__global__ __launch_bounds__(256) void scan_write(
    const int* __restrict__ cnt, const int* __restrict__ bsum,
    int* __restrict__ row_start, int* __restrict__ cursor, int n, int total) {
  __shared__ int wred[4];
  __shared__ int wsum[4];
  __shared__ int off_s;
  int b = blockIdx.x, tid = threadIdx.x;

  // offset = sum of bsum[0..b)  (gridDim.x <= 256)
  int v = (tid < b) ? bsum[tid] : 0;
#pragma unroll
  for (int o = 32; o > 0; o >>= 1) v += __shfl_down(v, o);
  if ((tid & 63) == 0) wred[tid >> 6] = v;
  __syncthreads();
  if (tid == 0) off_s = wred[0] + wred[1] + wred[2] + wred[3];

  int i = b * 256 + tid;
  int c = (i < n) ? cnt[i] : 0;
  int xv = c;  // inclusive scan within wave
#pragma unroll
  for (int o = 1; o < 64; o <<= 1) {
    int t = __shfl_up(xv, o);
    if ((tid & 63) >= o) xv += t;
  }
  if ((tid & 63) == 63) wsum[tid >> 6] = xv;
  __syncthreads();

  int w = tid >> 6;
  int woff = off_s;
  if (w > 0) woff += wsum[0];
  if (w > 1) woff += wsum[1];
  if (w > 2) woff += wsum[2];
  int excl = woff + xv - c;
  if (i < n) {
    row_start[i] = excl;
    cursor[i]    = excl;
  }
  if (i == 0) row_start[n] = total;
}

__global__ __launch_bounds__(256) void scatter_kernel(
    const int* __restrict__ ei, int* __restrict__ cursor,
    int* __restrict__ perm, int E) {
  int e = blockIdx.x * blockDim.x + threadIdx.x;
  if (e >= E) return;
  int pos = atomicAdd(&cursor[ei[E + e]], 1);
  perm[pos] = e;
}

// ---------------- Fused per-node attention (online softmax, no atomics) -----
// One wave per node; lane l covers channels 2l,2l+1 (head l>>3).
// Edge ids + src nodes for up to 64 edges are loaded IN PARALLEL across lanes
// (one coalesced load + one gather), then broadcast per-edge via __shfl with
// a uniform index (v_readlane) — removes the serial perm->ei->data chain.
// 4-edge unroll keeps 12 gathers in flight per step.
__global__ __launch_bounds__(256) void fused_attn(
    const float* __restrict__ qkv, const float* __restrict__ edge_attr,
    const int* __restrict__ ei, const int* __restrict__ row_start,
    const int* __restrict__ perm, float* __restrict__ agg, int N, int E) {
  int node = (blockIdx.x * blockDim.x + threadIdx.x) >> 6;
  if (node >= N) return;
  int lane = threadIdx.x & 63;
  int ch   = lane * 2;

  float2 q2 = *(const float2*)(qkv + (size_t)node * 384 + ch);

  float m = -INFINITY, l = 0.f;
  float2 acc = make_float2(0.f, 0.f);

  int beg  = row_start[node];
  int stop = row_start[node + 1];

  for (int c0 = beg; c0 < stop; c0 += 64) {
    int nc = min(64, stop - c0);
    int el = 0, sl = 0;
    if (c0 + lane < stop) {
      el = perm[c0 + lane];   // coalesced
      sl = ei[el];            // gather, parallel across lanes
    }
    int j = 0;
    for (; j + 4 <= nc; j += 4) {
      int e0 = __shfl(el, j),     e1 = __shfl(el, j + 1);
      int e2 = __shfl(el, j + 2), e3 = __shfl(el, j + 3);
      int s0 = __shfl(sl, j),     s1 = __shfl(sl, j + 1);
      int s2 = __shfl(sl, j + 2), s3 = __shfl(sl, j + 3);
      float2 k0 = *(const float2*)(qkv + (size_t)s0 * 384 + 128 + ch);
      float2 k1 = *(const float2*)(qkv + (size_t)s1 * 384 + 128 + ch);
      float2 k2 = *(const float2*)(qkv + (size_t)s2 * 384 + 128 + ch);
      float2 k3 = *(const float2*)(qkv + (size_t)s3 * 384 + 128 + ch);
      float2 a0 = *(const float2*)(edge_attr + (size_t)e0 * 128 + ch);
      float2 a1 = *(const float2*)(edge_attr + (size_t)e1 * 128 + ch);
      float2 a2 = *(const float2*)(edge_attr + (size_t)e2 * 128 + ch);
      float2 a3 = *(const float2*)(edge_attr + (size_t)e3 * 128 + ch);
      float2 v0 = *(const float2*)(qkv + (size_t)s0 * 384 + 256 + ch);
      float2 v1 = *(const float2*)(qkv + (size_t)s1 * 384 + 256 + ch);
      float2 v2 = *(const float2*)(qkv + (size_t)s2 * 384 + 256 + ch);
      float2 v3 = *(const float2*)(qkv + (size_t)s3 * 384 + 256 + ch);
      float p0 = q2.x * (k0.x + a0.x) + q2.y * (k0.y + a0.y);
      float p1 = q2.x * (k1.x + a1.x) + q2.y * (k1.y + a1.y);
      float p2 = q2.x * (k2.x + a2.x) + q2.y * (k2.y + a2.y);
      float p3 = q2.x * (k3.x + a3.x) + q2.y * (k3.y + a3.y);
      p0 += __shfl_xor(p0, 1); p1 += __shfl_xor(p1, 1);
      p2 += __shfl_xor(p2, 1); p3 += __shfl_xor(p3, 1);
      p0 += __shfl_xor(p0, 2); p1 += __shfl_xor(p1, 2);
      p2 += __shfl_xor(p2, 2); p3 += __shfl_xor(p3, 2);
      p0 += __shfl_xor(p0, 4); p1 += __shfl_xor(p1, 4);
      p2 += __shfl_xor(p2, 4); p3 += __shfl_xor(p3, 4);
      float sc0 = p0 * 0.25f, sc1 = p1 * 0.25f;
      float sc2 = p2 * 0.25f, sc3 = p3 * 0.25f;
      float mn = fmaxf(fmaxf(fmaxf(m, sc0), fmaxf(sc1, sc2)), sc3);
      float scale = __expf(m - mn);  // m=-inf first step -> 0, no NaN
      float pe0 = __expf(sc0 - mn), pe1 = __expf(sc1 - mn);
      float pe2 = __expf(sc2 - mn), pe3 = __expf(sc3 - mn);
      l = l * scale + pe0 + pe1 + pe2 + pe3;
      acc.x = acc.x * scale + pe0 * v0.x + pe1 * v1.x + pe2 * v2.x + pe3 * v3.x;
      acc.y = acc.y * scale + pe0 * v0.y + pe1 * v1.y + pe2 * v2.y + pe3 * v3.y;
      m = mn;
    }
    for (; j < nc; ++j) {
      int e0 = __shfl(el, j);
      int s0 = __shfl(sl, j);
      float2 kv = *(const float2*)(qkv + (size_t)s0 * 384 + 128 + ch);
      float2 ea = *(const float2*)(edge_attr + (size_t)e0 * 128 + ch);
      float2 vv = *(const float2*)(qkv + (size_t)s0 * 384 + 256 + ch);
      float p = q2.x * (kv.x + ea.x) + q2.y * (kv.y + ea.y);
      p += __shfl_xor(p, 1);
      p += __shfl_xor(p, 2);
      p += __shfl_xor(p, 4);
      float s  = p * 0.25f;
      float mn = fmaxf(m, s);
      float scale = __expf(m - mn);
      float pe    = __expf(s - mn);
      l = l * scale + pe;
      acc.x = acc.x * scale + pe * vv.x;
      acc.y = acc.y * scale + pe * vv.y;
      m = mn;
    }
  }
  float inv = 1.f / fmaxf(l, 1e-16f);
  float2 o = make_float2(acc.x * inv, acc.y * inv);
  *(float2*)(agg + (size_t)node * 128 + ch) = o;
}

extern "C" void kernel_launch(void* const* d_in, const int* in_sizes, int n_in,
                              void* d_out, int out_size, void* d_ws,
                              size_t ws_size, hipStream_t stream) {
  const float* x         = (const float*)d_in[0];
  const float* edge_attr = (const float*)d_in[1];
  const float* qkv_w     = (const float*)d_in[2];
  const float* qkv_b     = (const float*)d_in[3];
  const float* out_w     = (const float*)d_in[4];
  const float* out_b     = (const float*)d_in[5];
  const float* ln_g      = (const float*)d_in[6];
  const float* ln_b      = (const float*)d_in[7];
  const int*   ei        = (const int*)d_in[8];
  float* out = (float*)d_out;

  const int N = NN, E = NE;
  const int NB = (N + 255) / 256;  // 196
  float* qkv       = (float*)d_ws;                        // N*384 f
  float* agg       = qkv + (size_t)N * 384;               // N*128 f
  int*   cnt       = (int*)(agg + (size_t)N * 128);       // N
  int*   bsum      = cnt + N;                             // 256
  int*   row_start = bsum + 256;                          // N+1
  int*   cursor    = row_start + N + 1;                   // N
  int*   perm      = cursor + N;                          // E

  // --- CSR build ---
  hipMemsetAsync(cnt, 0, (size_t)N * 4, stream);
  count_kernel<<<(E + 255) / 256, 256, 0, stream>>>(ei, cnt, E);
  block_sums<<<NB, 256, 0, stream>>>(cnt, bsum, N);
  scan_write<<<NB, 256, 0, stream>>>(cnt, bsum, row_start, cursor, N, E);
  scatter_kernel<<<(E + 255) / 256, 256, 0, stream>>>(ei, cursor, perm, E);

  // --- 1. LayerNorm + QKV projection (fused) ---
  dim3 g1(NB, 384 / 64);
  ln_qkv<<<g1, 256, 0, stream>>>(x, ln_g, ln_b, qkv_w, qkv_b, qkv, N);

  // --- 2. fused attention (scores + softmax + aggregate) ---
  fused_attn<<<(N * 64 + 255) / 256, 256, 0, stream>>>(
      qkv, edge_attr, ei, row_start, perm, agg, N, E);

  // --- 3. output projection + bias + residual ---
  dim3 g2(NB, 128 / 64);
  gemm_rw<<<g2, 256, 0, stream>>>(agg, out_w, out_b, x, out, N, 128);
}